// Round 7
// baseline (264.596 us; speedup 1.0000x reference)
//
#include <hip/hip_runtime.h>
#include <math.h>

// (B,C,H,W)=(8,256,64,64); NH=NP=4, d=64, Nq=4096, M=B*Nq=32768.
namespace {
constexpr int kC = 256;
constexpr int kNq = 4096;
constexpr int kM = 32768;
}

typedef __attribute__((ext_vector_type(8))) short short8;
typedef __attribute__((ext_vector_type(4))) short short4v;
typedef __attribute__((ext_vector_type(4))) float f32x4;

__device__ inline unsigned short f2bf(float f) {
  union { float f; unsigned u; } v; v.f = f;
  unsigned r = (v.u + 0x7FFFu + ((v.u >> 16) & 1u)) >> 16;  // RNE
  return (unsigned short)r;
}
__device__ inline float uasf(unsigned u) {
  union { unsigned u; float f; } v; v.u = u; return v.f;
}

// -----------------------------------------------------------------------------
// K0: weight prep (bf16 + transpose) + QP table. (unchanged)
// -----------------------------------------------------------------------------
__global__ __launch_bounds__(256)
void prep_weights_kernel(const float* __restrict__ Wv, const float* __restrict__ Wo,
                         const float* __restrict__ Woff, const float* __restrict__ Watt,
                         const float* __restrict__ boff, const float* __restrict__ batt,
                         const float* __restrict__ ps,
                         unsigned short* __restrict__ WvT, unsigned short* __restrict__ WoT,
                         unsigned short* __restrict__ WoaT, float* __restrict__ QP) {
  __shared__ unsigned short Aq[16][264];
  const int blk = blockIdx.x;
  const int tid = threadIdx.x;
  const int i = blk * 256 + tid;  // 256 blocks -> i < 65536
  {
    const int n = i >> 8, k = i & 255;
    WvT[i] = f2bf(Wv[k * 256 + n]);
    WoT[i] = f2bf(Wo[k * 256 + n]);
  }
  if (i < 16384) {
    const int j = i >> 8, k = i & 255;
    float v = 0.f;
    if (j < 32) v = Woff[k * 32 + j];
    else if (j < 48) v = Watt[k * 16 + (j - 32)];
    WoaT[i] = f2bf(v);
  }

  // --- QP tile: 16 queries q = blk*16 .. +15, thread = channel ---
  const float scale = ps[0];
  const int i2 = (tid < 128) ? tid : (tid - 128);
  const float invf = powf(10000.f, -(float)(2 * i2) * (1.f / 256.f));
  const int q0 = blk * 16;
  const float a0 = (float)q0 * invf;
  float sv = sinf(a0), cv = cosf(a0);
  const float sd = sinf(invf), cd = cosf(invf);
#pragma unroll
  for (int q = 0; q < 16; ++q) {
    Aq[q][tid] = f2bf(((tid < 128) ? sv : cv) * scale);
    const float ns = sv * cd + cv * sd;
    const float nc = cv * cd - sv * sd;
    sv = ns; cv = nc;
  }
  __syncthreads();

  const int lane = tid & 63, w = tid >> 6;
  const int l15 = lane & 15, quad = lane >> 4;
  if (w < 3) {  // n-frag w covers n = w*16 .. +15 (48 live columns)
    f32x4 acc = (f32x4){0.f, 0.f, 0.f, 0.f};
#pragma unroll
    for (int s = 0; s < 8; ++s) {
      const short8 af = *(const short8*)&Aq[l15][s * 32 + quad * 8];
      short8 wf;
#pragma unroll
      for (int j = 0; j < 8; ++j) {
        const int k = s * 32 + quad * 8 + j;
        wf[j] = (short)f2bf((w < 2) ? Woff[k * 32 + w * 16 + l15]
                                    : Watt[k * 16 + l15]);
      }
      acc = __builtin_amdgcn_mfma_f32_16x16x32_bf16(af, wf, acc, 0, 0, 0);
    }
    const int n = w * 16 + l15;
    const float bn = (n < 32) ? boff[n] : batt[n - 32];
#pragma unroll
    for (int r = 0; r < 4; ++r) {
      const int q = q0 + quad * 4 + r;
      QP[q * 48 + n] = acc[r] + bn;
    }
  }
}

// -----------------------------------------------------------------------------
// K1: merged LN+transpose+GEMM. REVERTED to the r2/v6 config -- the best
// measured K1 (40.9 us). r3-r6 established that neither occupancy (27-44%),
// VGPR budget (32/40/64), tile size (32q/64q) nor barrier count moves it;
// every deviation from this config regressed. 1024 blocks, 64q tiles:
//   mode 0: V  = LN2(x2^T) @ W_val + b_val           (bf16 out)
//   mode 1: RAW= LN1(x1^T) @ [W_off|W_att] + QP[q]   (fp32 out, 48 cols)
// XCD balance: mode=(blk>>3)&1, tile=(blk&7)|((blk>>4)<<3) (bijective).
// -----------------------------------------------------------------------------
__global__ __launch_bounds__(256, 4)
void fused_ln_gemm_kernel(const float* __restrict__ x1, const float* __restrict__ x2,
                          const float* __restrict__ ln1_g, const float* __restrict__ ln1_b,
                          const float* __restrict__ ln2_g, const float* __restrict__ ln2_b,
                          const unsigned short* __restrict__ WvT,
                          const float* __restrict__ b_val, unsigned short* __restrict__ V,
                          const unsigned short* __restrict__ WoaT,
                          const float* __restrict__ QP, float* __restrict__ RAW) {
  __shared__ unsigned short As[64][264];   // 33792 B (normalized bf16, q x c)
  __shared__ float psum[2][32][4];         // 1024 B
  __shared__ float psq[2][32][4];          // 1024 B
  __shared__ float smean[64];
  __shared__ float srstd[64];

  const int blk = blockIdx.x;
  const int mode = (blk >> 3) & 1;         // 0: val path (x2), 1: offatt (x1)
  const int tile = (blk & 7) | ((blk >> 4) << 3);   // [0,512)
  const int m0 = tile * 64;
  const int b = m0 >> 12;
  const int n0 = m0 & 4095;
  const int tid = threadIdx.x;
  const int lane = tid & 63, w = tid >> 6;
  const int l7 = tid & 7;                  // q-slice within group
  const int q4 = l7 * 4;
  const int cb8 = (tid >> 3) * 8;          // this thread's 8 consecutive channels
  const float* Xb = (mode ? x1 : x2) + (size_t)b * kC * kNq;
  const float* gptr = mode ? ln1_g : ln2_g;
  const float* bptr = mode ? ln1_b : ln2_b;

  float4 gm[2], bv[2];
  gm[0] = *(const float4*)&gptr[cb8];
  gm[1] = *(const float4*)&gptr[cb8 + 4];
  bv[0] = *(const float4*)&bptr[cb8];
  bv[1] = *(const float4*)&bptr[cb8 + 4];

  // ---- all 16 global float4 loads upfront ----
  float4 v[16];
#pragma unroll
  for (int g = 0; g < 2; ++g)
#pragma unroll
    for (int it = 0; it < 8; ++it)
      v[g * 8 + it] = *(const float4*)&Xb[(size_t)(cb8 + it) * kNq + n0 + g * 32 + q4];

  // ---- stats in registers ----
  float s[2][4] = {}, sq[2][4] = {};
#pragma unroll
  for (int g = 0; g < 2; ++g)
#pragma unroll
    for (int it = 0; it < 8; ++it) {
      const float* e = (const float*)&v[g * 8 + it];
#pragma unroll
      for (int j = 0; j < 4; ++j) {
        s[g][j] += e[j];
        sq[g][j] += e[j] * e[j];
      }
    }
  // butterfly over lane bits 3..5 (sums the 8 channel-groups in this wave)
#pragma unroll
  for (int d = 8; d <= 32; d <<= 1)
#pragma unroll
    for (int g = 0; g < 2; ++g)
#pragma unroll
      for (int j = 0; j < 4; ++j) {
        s[g][j] += __shfl_xor(s[g][j], d);
        sq[g][j] += __shfl_xor(sq[g][j], d);
      }
  if (lane < 8) {
#pragma unroll
    for (int g = 0; g < 2; ++g)
#pragma unroll
      for (int j = 0; j < 4; ++j) {
        psum[g][q4 + j][w] = s[g][j];
        psq[g][q4 + j][w] = sq[g][j];
      }
  }
  __syncthreads();
  if (tid < 64) {
    const int g = tid >> 5, qq = tid & 31;
    float S = 0.f, Q = 0.f;
#pragma unroll
    for (int ww = 0; ww < 4; ++ww) { S += psum[g][qq][ww]; Q += psq[g][qq][ww]; }
    const float m = S * (1.f / 256.f);
    const float var = Q * (1.f / 256.f) - m * m;
    smean[tid] = m;
    srstd[tid] = rsqrtf(var + 1e-5f);
  }
  __syncthreads();

  // ---- normalize from registers, b64 writes to As[q][c] ----
#pragma unroll
  for (int g = 0; g < 2; ++g) {
    const float4 mn = *(const float4*)&smean[g * 32 + q4];
    const float4 rs = *(const float4*)&srstd[g * 32 + q4];
    const float* mnp = (const float*)&mn;
    const float* rsp = (const float*)&rs;
#pragma unroll
    for (int j = 0; j < 4; ++j) {
      const int row = g * 32 + q4 + j;
      short4v pk0, pk1;
#pragma unroll
      for (int it = 0; it < 4; ++it) {
        const float e0 = ((const float*)&v[g * 8 + it])[j];
        const float e1 = ((const float*)&v[g * 8 + 4 + it])[j];
        pk0[it] = (short)f2bf((e0 - mnp[j]) * rsp[j] * ((const float*)gm)[it] + ((const float*)bv)[it]);
        pk1[it] = (short)f2bf((e1 - mnp[j]) * rsp[j] * ((const float*)gm)[4 + it] + ((const float*)bv)[4 + it]);
      }
      *(short4v*)&As[row][cb8] = pk0;
      *(short4v*)&As[row][cb8 + 4] = pk1;
    }
  }
  __syncthreads();

  const int l15 = lane & 15, quad = lane >> 4;

  if (mode == 0) {
    // 64x256 GEMM: wave w -> n-range w*64; W frags streamed from L2.
    // acc[i][j] = mfma(wf[j], af[i]) -> lane holds col m=i*16+l15 (fixed) and
    // rows n = w*64 + j*16 + quad*4 + r (4 consecutive n per (i,j)).
    f32x4 acc[4][4];
#pragma unroll
    for (int i = 0; i < 4; ++i)
#pragma unroll
      for (int j = 0; j < 4; ++j) acc[i][j] = (f32x4){0.f, 0.f, 0.f, 0.f};
#pragma unroll
    for (int s2 = 0; s2 < 8; ++s2) {
      short8 af[4], wf[4];
#pragma unroll
      for (int t = 0; t < 4; ++t) af[t] = *(const short8*)&As[t * 16 + l15][s2 * 32 + quad * 8];
#pragma unroll
      for (int t = 0; t < 4; ++t)
        wf[t] = *(const short8*)&WvT[(size_t)(w * 64 + t * 16 + l15) * 256 + s2 * 32 + quad * 8];
#pragma unroll
      for (int i = 0; i < 4; ++i)
#pragma unroll
        for (int j = 0; j < 4; ++j)
          acc[i][j] = __builtin_amdgcn_mfma_f32_16x16x32_bf16(wf[j], af[i], acc[i][j], 0, 0, 0);
    }
    float4 bv4[4];
#pragma unroll
    for (int j = 0; j < 4; ++j)
      bv4[j] = *(const float4*)&b_val[w * 64 + j * 16 + quad * 4];
#pragma unroll
    for (int i = 0; i < 4; ++i) {
      const int m = m0 + i * 16 + l15;
#pragma unroll
      for (int j = 0; j < 4; ++j) {
        const float* bp = (const float*)&bv4[j];
        uint2 pk;
        pk.x = (unsigned)f2bf(acc[i][j][0] + bp[0]) | ((unsigned)f2bf(acc[i][j][1] + bp[1]) << 16);
        pk.y = (unsigned)f2bf(acc[i][j][2] + bp[2]) | ((unsigned)f2bf(acc[i][j][3] + bp[3]) << 16);
        *(uint2*)&V[(size_t)m * 256 + w * 64 + j * 16 + quad * 4] = pk;
      }
    }
  } else {
    // 64q x 48n: wave w owns q-frag w; j-frags 0..2 cover n=0..47.
    // acc[j] = mfma(wf[j], af) -> lane holds col q=w*16+l15 (fixed) and
    // rows n = j*16 + quad*4 + r (4 consecutive n per j) -> float4 stores.
    f32x4 acc[3];
#pragma unroll
    for (int j = 0; j < 3; ++j) acc[j] = (f32x4){0.f, 0.f, 0.f, 0.f};
#pragma unroll
    for (int s2 = 0; s2 < 8; ++s2) {
      short8 af = *(const short8*)&As[w * 16 + l15][s2 * 32 + quad * 8];
      short8 wf[3];
#pragma unroll
      for (int t = 0; t < 3; ++t)
        wf[t] = *(const short8*)&WoaT[(size_t)(t * 16 + l15) * 256 + s2 * 32 + quad * 8];
#pragma unroll
      for (int j = 0; j < 3; ++j)
        acc[j] = __builtin_amdgcn_mfma_f32_16x16x32_bf16(wf[j], af, acc[j], 0, 0, 0);
    }
    const int m = m0 + w * 16 + l15;
    const int q = n0 + w * 16 + l15;
#pragma unroll
    for (int j = 0; j < 3; ++j) {
      const int nb = j * 16 + quad * 4;
      const float4 qp = *(const float4*)&QP[q * 48 + nb];
      float4 o;
      o.x = acc[j][0] + qp.x;
      o.y = acc[j][1] + qp.y;
      o.z = acc[j][2] + qp.z;
      o.w = acc[j][3] + qp.w;
      *(float4*)&RAW[(size_t)m * 48 + nb] = o;
    }
  }
}

// -----------------------------------------------------------------------------
// K2 v6: fused sampling + out-projection + residual. OCCUPANCY + chain fix.
// Old: LDS = Bs(33.8K) + sidx/swgt/ot(32.8K) = 66.6K -> 2 blocks/CU for a
// latency-bound L2 gather. v6: (a) S1 kept entirely in registers -- the S2
// thread mapping is changed so each thread owns ONE (q,h) for both phases
// (cidx[16]/cwgt[16]), deleting sidx/swgt and one barrier; (b) S2 loops the
// 8 c-slices per thread (identical loads + FMA order -> bit-identical);
// (c) epilogue fp32 tile ot (32K) aliased onto Bs (dead after MFMA reads,
// guarded by the existing barrier). LDS 66.6K -> 33.8K -> 4 blocks/CU.
// -----------------------------------------------------------------------------
__global__ __launch_bounds__(256, 4)
void sample_out_kernel(const float* __restrict__ RAW, const unsigned short* __restrict__ V,
                       const unsigned short* __restrict__ Wt,  // [256][256] WoT
                       const float* __restrict__ bias, const float* __restrict__ x2,
                       float* __restrict__ OUT) {
  __shared__ __align__(16) char smem[64 * 264 * 2];       // 33792 B
  unsigned short (*Bs)[264] = (unsigned short (*)[264])smem;  // AO tile (q x c)
  float* ot = (float*)smem;                               // [128][64] fp32 (epilogue, aliased)

  const int blk = blockIdx.x;
  const int b = blk & 7;
  const int tile = blk >> 3;                     // 64 q-tiles per batch
  const int m0 = b * 4096 + tile * 64;
  const int tid = threadIdx.x;

  // ---- S1 (registers): this thread owns (q_l, h) for S1 AND S2 ----
  const int q_l = tid >> 2, h = tid & 3;
  int cidx[16];
  float cwgt[16];
  {
    const int m = m0 + q_l;
    const float* raw = RAW + (size_t)m * 48;
    const float4 att = *(const float4*)&raw[32 + h * 4];
    const float mx = fmaxf(fmaxf(att.x, att.y), fmaxf(att.z, att.w));
    const float e0 = expf(att.x - mx), e1 = expf(att.y - mx);
    const float e2 = expf(att.z - mx), e3 = expf(att.w - mx);
    const float den = e0 + e1 + e2 + e3;
    const float4 oA = *(const float4*)&raw[h * 8];
    const float4 oB = *(const float4*)&raw[h * 8 + 4];
    const float oxs[4] = {oA.x, oA.z, oB.x, oB.z};
    const float oys[4] = {oA.y, oA.w, oB.y, oB.w};
    const float es[4] = {e0, e1, e2, e3};
    const float fx0 = (float)(m & 63);           // W=64 cancels the normalizer
    const float fy0 = (float)((m >> 6) & 63);
#pragma unroll
    for (int p = 0; p < 4; ++p) {
      const float attp = es[p] / den;
      const float px = fx0 + oxs[p];
      const float py = fy0 + oys[p];
      const float fx = floorf(px), fy = floorf(py);
      const float wx = px - fx, wy = py - fy;
      const int x0 = (int)fx, y0 = (int)fy;
#pragma unroll
      for (int c = 0; c < 4; ++c) {
        const int dx = c & 1, dy = c >> 1;
        const int xx = x0 + dx, yy = y0 + dy;
        const bool valid = (xx >= 0) & (xx < 64) & (yy >= 0) & (yy < 64);
        const float wc = (dx ? wx : 1.f - wx) * (dy ? wy : 1.f - wy) * attp;
        cwgt[p * 4 + c] = valid ? wc : 0.f;
        const int xc = min(max(xx, 0), 63), yc = min(max(yy, 0), 63);
        cidx[p * 4 + c] = (yc * 64 + xc) * (kC * 2);   // byte offset into V rows
      }
    }
  }

  // ---- S2: gather + accumulate -> Bs (bf16), 8 c-slices per thread ----
  const char* vb = (const char*)(V + (size_t)b * kNq * kC + h * 64);
#pragma unroll
  for (int c8 = 0; c8 < 8; ++c8) {
    float acc[8] = {};
#pragma unroll
    for (int p = 0; p < 4; ++p)
#pragma unroll
      for (int c = 0; c < 4; ++c) {
        const int k = p * 4 + c;
        const uint4 u = *(const uint4*)(vb + cidx[k] + c8 * 16);
        const float w = cwgt[k];
        acc[0] = fmaf(w, uasf(u.x << 16), acc[0]);
        acc[1] = fmaf(w, uasf(u.x & 0xffff0000u), acc[1]);
        acc[2] = fmaf(w, uasf(u.y << 16), acc[2]);
        acc[3] = fmaf(w, uasf(u.y & 0xffff0000u), acc[3]);
        acc[4] = fmaf(w, uasf(u.z << 16), acc[4]);
        acc[5] = fmaf(w, uasf(u.z & 0xffff0000u), acc[5]);
        acc[6] = fmaf(w, uasf(u.w << 16), acc[6]);
        acc[7] = fmaf(w, uasf(u.w & 0xffff0000u), acc[7]);
      }
    short8 outv;
#pragma unroll
    for (int e = 0; e < 8; ++e) outv[e] = (short)f2bf(acc[e]);
    *(short8*)&Bs[q_l][h * 64 + c8 * 8] = outv;
  }
  __syncthreads();

  // ---- MFMA: wave w -> c-range w*64 ----
  const int lane = tid & 63, w = tid >> 6;
  const int l15 = lane & 15, quad = lane >> 4;
  f32x4 acc[4][4];
#pragma unroll
  for (int i = 0; i < 4; ++i)
#pragma unroll
    for (int j = 0; j < 4; ++j) acc[i][j] = (f32x4){0.f, 0.f, 0.f, 0.f};
#pragma unroll
  for (int s = 0; s < 8; ++s) {
    short8 wf[4], bf[4];
#pragma unroll
    for (int t = 0; t < 4; ++t)
      wf[t] = *(const short8*)&Wt[(size_t)(w * 64 + t * 16 + l15) * 256 + s * 32 + quad * 8];
#pragma unroll
    for (int t = 0; t < 4; ++t) bf[t] = *(const short8*)&Bs[t * 16 + l15][s * 32 + quad * 8];
#pragma unroll
    for (int i = 0; i < 4; ++i)
#pragma unroll
      for (int j = 0; j < 4; ++j)
        acc[i][j] = __builtin_amdgcn_mfma_f32_16x16x32_bf16(wf[i], bf[j], acc[i][j], 0, 0, 0);
  }

  // ---- Epilogue: LDS-staged transpose (ot aliases Bs) -> float4 stores ----
  // First __syncthreads() below guarantees every wave has finished its MFMA
  // reads of Bs before any lane overwrites the region as ot.
  const int whalf = w >> 1;
  const int clbase = (w & 1) * 64;
  for (int ch = 0; ch < 2; ++ch) {
    __syncthreads();
    if (whalf == ch) {
#pragma unroll
      for (int i = 0; i < 4; ++i)
#pragma unroll
        for (int j = 0; j < 4; ++j)
#pragma unroll
          for (int r = 0; r < 4; ++r)
            ot[(clbase + i * 16 + quad * 4 + r) * 64 + j * 16 + l15] = acc[i][j][r];
    }
    __syncthreads();
#pragma unroll
    for (int t = 0; t < 8; ++t) {
      const int lin = t * 256 + tid;
      const int cl = lin >> 4, q4 = (lin & 15) * 4;
      const int c = ch * 128 + cl;
      const size_t rowbase = ((size_t)b * 256 + c) * 4096 + tile * 64;
      const float4 xv = *(const float4*)&x2[rowbase + q4];
      const float bc = bias[c];
      float4 o;
      o.x = ot[cl * 64 + q4 + 0] + bc + xv.x;
      o.y = ot[cl * 64 + q4 + 1] + bc + xv.y;
      o.z = ot[cl * 64 + q4 + 2] + bc + xv.z;
      o.w = ot[cl * 64 + q4 + 3] + bc + xv.w;
      *(float4*)&OUT[rowbase + q4] = o;
    }
  }
}

// -----------------------------------------------------------------------------
extern "C" void kernel_launch(void* const* d_in, const int* in_sizes, int n_in,
                              void* d_out, int out_size, void* d_ws, size_t ws_size,
                              hipStream_t stream) {
  const float* x1 = (const float*)d_in[0];
  const float* x2 = (const float*)d_in[1];
  const float* ln1_g = (const float*)d_in[2];
  const float* ln1_b = (const float*)d_in[3];
  const float* ln2_g = (const float*)d_in[4];
  const float* ln2_b = (const float*)d_in[5];
  const float* pos_scale = (const float*)d_in[6];
  const float* W_off = (const float*)d_in[7];
  const float* b_off = (const float*)d_in[8];
  const float* W_att = (const float*)d_in[9];
  const float* b_att = (const float*)d_in[10];
  const float* W_val = (const float*)d_in[11];
  const float* b_val = (const float*)d_in[12];
  const float* W_out = (const float*)d_in[13];
  const float* b_out = (const float*)d_in[14];
  float* out = (float*)d_out;

  char* ws = (char*)d_ws;
  const size_t plane2 = (size_t)kM * kC * sizeof(unsigned short);  // 16 MiB
  unsigned short* Vb   = (unsigned short*)(ws);
  float* RAW           = (float*)(ws + plane2);
  unsigned short* WvT  = (unsigned short*)(ws + plane2 + (size_t)kM * 48 * 4);
  unsigned short* WoT  = WvT + 65536;
  unsigned short* WoaT = WoT + 65536;
  float* QP            = (float*)(WoaT + 16384);   // [4096][48] fp32

  prep_weights_kernel<<<256, 256, 0, stream>>>(W_val, W_out, W_off, W_att,
                                               b_off, b_att, pos_scale,
                                               WvT, WoT, WoaT, QP);
  fused_ln_gemm_kernel<<<1024, 256, 0, stream>>>(x1, x2, ln1_g, ln1_b, ln2_g, ln2_b,
                                                 WvT, b_val, Vb, WoaT, QP, RAW);
  sample_out_kernel<<<512, 256, 0, stream>>>(RAW, Vb, WoT, b_out, x2, out);
}

// Round 8
// 174.205 us; speedup vs baseline: 1.5189x; 1.5189x over previous
//
#include <hip/hip_runtime.h>
#include <math.h>

// (B,C,H,W)=(8,256,64,64); NH=NP=4, d=64, Nq=4096, M=B*Nq=32768.
namespace {
constexpr int kC = 256;
constexpr int kNq = 4096;
constexpr int kM = 32768;
}

typedef __attribute__((ext_vector_type(8))) short short8;
typedef __attribute__((ext_vector_type(4))) short short4v;
typedef __attribute__((ext_vector_type(4))) float f32x4;

__device__ inline unsigned short f2bf(float f) {
  union { float f; unsigned u; } v; v.f = f;
  unsigned r = (v.u + 0x7FFFu + ((v.u >> 16) & 1u)) >> 16;  // RNE
  return (unsigned short)r;
}
__device__ inline float uasf(unsigned u) {
  union { unsigned u; float f; } v; v.u = u; return v.f;
}

// -----------------------------------------------------------------------------
// K0: weight prep (bf16 + transpose) + QP table.
// QP[q][n] = (qpos[q]*scale) @ [W_off|W_att][:,n] + bias[n].
// v2: QP spread over ALL 256 blocks (16 q each); sin/cos via rotation
// recurrence (one sinf/cosf pair + 16 rotations) instead of 16 libm calls.
// -----------------------------------------------------------------------------
__global__ __launch_bounds__(256)
void prep_weights_kernel(const float* __restrict__ Wv, const float* __restrict__ Wo,
                         const float* __restrict__ Woff, const float* __restrict__ Watt,
                         const float* __restrict__ boff, const float* __restrict__ batt,
                         const float* __restrict__ ps,
                         unsigned short* __restrict__ WvT, unsigned short* __restrict__ WoT,
                         unsigned short* __restrict__ WoaT, float* __restrict__ QP) {
  __shared__ unsigned short Aq[16][264];
  const int blk = blockIdx.x;
  const int tid = threadIdx.x;
  const int i = blk * 256 + tid;  // 256 blocks -> i < 65536
  {
    const int n = i >> 8, k = i & 255;
    WvT[i] = f2bf(Wv[k * 256 + n]);
    WoT[i] = f2bf(Wo[k * 256 + n]);
  }
  if (i < 16384) {
    const int j = i >> 8, k = i & 255;
    float v = 0.f;
    if (j < 32) v = Woff[k * 32 + j];
    else if (j < 48) v = Watt[k * 16 + (j - 32)];
    WoaT[i] = f2bf(v);
  }

  // --- QP tile: 16 queries q = blk*16 .. +15, thread = channel ---
  const float scale = ps[0];
  const int i2 = (tid < 128) ? tid : (tid - 128);
  const float invf = powf(10000.f, -(float)(2 * i2) * (1.f / 256.f));
  const int q0 = blk * 16;
  const float a0 = (float)q0 * invf;
  float sv = sinf(a0), cv = cosf(a0);
  const float sd = sinf(invf), cd = cosf(invf);
#pragma unroll
  for (int q = 0; q < 16; ++q) {
    Aq[q][tid] = f2bf(((tid < 128) ? sv : cv) * scale);
    const float ns = sv * cd + cv * sd;
    const float nc = cv * cd - sv * sd;
    sv = ns; cv = nc;
  }
  __syncthreads();

  const int lane = tid & 63, w = tid >> 6;
  const int l15 = lane & 15, quad = lane >> 4;
  if (w < 3) {  // n-frag w covers n = w*16 .. +15 (48 live columns)
    f32x4 acc = (f32x4){0.f, 0.f, 0.f, 0.f};
#pragma unroll
    for (int s = 0; s < 8; ++s) {
      const short8 af = *(const short8*)&Aq[l15][s * 32 + quad * 8];
      short8 wf;
#pragma unroll
      for (int j = 0; j < 8; ++j) {
        const int k = s * 32 + quad * 8 + j;
        wf[j] = (short)f2bf((w < 2) ? Woff[k * 32 + w * 16 + l15]
                                    : Watt[k * 16 + l15]);
      }
      acc = __builtin_amdgcn_mfma_f32_16x16x32_bf16(af, wf, acc, 0, 0, 0);
    }
    const int n = w * 16 + l15;
    const float bn = (n < 32) ? boff[n] : batt[n - 32];
#pragma unroll
    for (int r = 0; r < 4; ++r) {
      const int q = q0 + quad * 4 + r;
      QP[q * 48 + n] = acc[r] + bn;
    }
  }
}

// -----------------------------------------------------------------------------
// K1: merged LN+transpose+GEMM v4. 1024 blocks, mode = blockIdx&1:
//   mode 0: V  = LN2(x2^T) @ W_val + b_val           (bf16 out)
//   mode 1: RAW= LN1(x1^T) @ [W_off|W_att] + QP[q]   (fp32 out, 48 cols)
// Phase A v4 (NO LDS scratch): thread owns 8 consecutive channels x 4 queries
// in registers (c=(tid>>3)*8+it, q=(tid&7)*4+j). Stats: register accumulate +
// shfl_xor butterfly (lane bits 3-5) + psum cross-wave exchange. Normalize
// from registers, write As[q][c] directly as b64 short4 (4/bank = optimal).
// LDS 35.5 KB -> 4 blocks/CU (16 waves); 3 barriers total.
// Frag layouts [verified r2-r7]: A/B lane = [idx=lane&15][k=quad*8+j];
// C/D: col(l15) = 2nd operand idx, row(quad*4+reg) = 1st operand idx.
// [Session r0-r7: epilogue vectorization, XCD remap, occupancy x2, VGPR
// budget, tile 32q, barrier removal -- all measured neutral or worse; this
// exact config is the best measured (174.4 us total). Reverted verbatim.]
// -----------------------------------------------------------------------------
__global__ __launch_bounds__(256, 4)
void fused_ln_gemm_kernel(const float* __restrict__ x1, const float* __restrict__ x2,
                          const float* __restrict__ ln1_g, const float* __restrict__ ln1_b,
                          const float* __restrict__ ln2_g, const float* __restrict__ ln2_b,
                          const unsigned short* __restrict__ WvT,
                          const float* __restrict__ b_val, unsigned short* __restrict__ V,
                          const unsigned short* __restrict__ WoaT,
                          const float* __restrict__ QP, float* __restrict__ RAW) {
  __shared__ unsigned short As[64][264];   // 33792 B (normalized bf16, q x c)
  __shared__ float psum[2][32][4];         // 1024 B
  __shared__ float psq[2][32][4];          // 1024 B
  __shared__ float smean[64];
  __shared__ float srstd[64];

  const int mode = blockIdx.x & 1;         // 0: val path (x2), 1: offatt (x1)
  const int m0 = (blockIdx.x >> 1) * 64;
  const int b = m0 >> 12;
  const int n0 = m0 & 4095;
  const int tid = threadIdx.x;
  const int lane = tid & 63, w = tid >> 6;
  const int l7 = tid & 7;                  // q-slice within group
  const int q4 = l7 * 4;
  const int cb8 = (tid >> 3) * 8;          // this thread's 8 consecutive channels
  const float* Xb = (mode ? x1 : x2) + (size_t)b * kC * kNq;
  const float* gptr = mode ? ln1_g : ln2_g;
  const float* bptr = mode ? ln1_b : ln2_b;

  float4 gm[2], bv[2];
  gm[0] = *(const float4*)&gptr[cb8];
  gm[1] = *(const float4*)&gptr[cb8 + 4];
  bv[0] = *(const float4*)&bptr[cb8];
  bv[1] = *(const float4*)&bptr[cb8 + 4];

  // ---- all 16 global float4 loads upfront ----
  float4 v[16];
#pragma unroll
  for (int g = 0; g < 2; ++g)
#pragma unroll
    for (int it = 0; it < 8; ++it)
      v[g * 8 + it] = *(const float4*)&Xb[(size_t)(cb8 + it) * kNq + n0 + g * 32 + q4];

  // ---- stats in registers ----
  float s[2][4] = {}, sq[2][4] = {};
#pragma unroll
  for (int g = 0; g < 2; ++g)
#pragma unroll
    for (int it = 0; it < 8; ++it) {
      const float* e = (const float*)&v[g * 8 + it];
#pragma unroll
      for (int j = 0; j < 4; ++j) {
        s[g][j] += e[j];
        sq[g][j] += e[j] * e[j];
      }
    }
  // butterfly over lane bits 3..5 (sums the 8 channel-groups in this wave)
#pragma unroll
  for (int d = 8; d <= 32; d <<= 1)
#pragma unroll
    for (int g = 0; g < 2; ++g)
#pragma unroll
      for (int j = 0; j < 4; ++j) {
        s[g][j] += __shfl_xor(s[g][j], d);
        sq[g][j] += __shfl_xor(sq[g][j], d);
      }
  if (lane < 8) {
#pragma unroll
    for (int g = 0; g < 2; ++g)
#pragma unroll
      for (int j = 0; j < 4; ++j) {
        psum[g][q4 + j][w] = s[g][j];
        psq[g][q4 + j][w] = sq[g][j];
      }
  }
  __syncthreads();
  if (tid < 64) {
    const int g = tid >> 5, qq = tid & 31;
    float S = 0.f, Q = 0.f;
#pragma unroll
    for (int ww = 0; ww < 4; ++ww) { S += psum[g][qq][ww]; Q += psq[g][qq][ww]; }
    const float m = S * (1.f / 256.f);
    const float var = Q * (1.f / 256.f) - m * m;
    smean[tid] = m;
    srstd[tid] = rsqrtf(var + 1e-5f);
  }
  __syncthreads();

  // ---- normalize from registers, b64 writes to As[q][c] ----
#pragma unroll
  for (int g = 0; g < 2; ++g) {
    const float4 mn = *(const float4*)&smean[g * 32 + q4];
    const float4 rs = *(const float4*)&srstd[g * 32 + q4];
    const float* mnp = (const float*)&mn;
    const float* rsp = (const float*)&rs;
#pragma unroll
    for (int j = 0; j < 4; ++j) {
      const int row = g * 32 + q4 + j;
      short4v pk0, pk1;
#pragma unroll
      for (int it = 0; it < 4; ++it) {
        const float e0 = ((const float*)&v[g * 8 + it])[j];
        const float e1 = ((const float*)&v[g * 8 + 4 + it])[j];
        pk0[it] = (short)f2bf((e0 - mnp[j]) * rsp[j] * ((const float*)gm)[it] + ((const float*)bv)[it]);
        pk1[it] = (short)f2bf((e1 - mnp[j]) * rsp[j] * ((const float*)gm)[4 + it] + ((const float*)bv)[4 + it]);
      }
      *(short4v*)&As[row][cb8] = pk0;
      *(short4v*)&As[row][cb8 + 4] = pk1;
    }
  }
  __syncthreads();

  const int l15 = lane & 15, quad = lane >> 4;

  if (mode == 0) {
    // 64x256 GEMM: wave w -> n-range w*64; W frags streamed from L2
    f32x4 acc[4][4];
#pragma unroll
    for (int i = 0; i < 4; ++i)
#pragma unroll
      for (int j = 0; j < 4; ++j) acc[i][j] = (f32x4){0.f, 0.f, 0.f, 0.f};
#pragma unroll
    for (int s2 = 0; s2 < 8; ++s2) {
      short8 af[4], wf[4];
#pragma unroll
      for (int t = 0; t < 4; ++t) af[t] = *(const short8*)&As[t * 16 + l15][s2 * 32 + quad * 8];
#pragma unroll
      for (int t = 0; t < 4; ++t)
        wf[t] = *(const short8*)&WvT[(size_t)(w * 64 + t * 16 + l15) * 256 + s2 * 32 + quad * 8];
#pragma unroll
      for (int i = 0; i < 4; ++i)
#pragma unroll
        for (int j = 0; j < 4; ++j)
          acc[i][j] = __builtin_amdgcn_mfma_f32_16x16x32_bf16(af[i], wf[j], acc[i][j], 0, 0, 0);
    }
#pragma unroll
    for (int i = 0; i < 4; ++i)
#pragma unroll
      for (int j = 0; j < 4; ++j) {
        const int n = w * 64 + j * 16 + l15;
        const float bn = b_val[n];
#pragma unroll
        for (int r = 0; r < 4; ++r) {
          const int m = m0 + i * 16 + quad * 4 + r;
          V[(size_t)m * 256 + n] = f2bf(acc[i][j][r] + bn);
        }
      }
  } else {
    // 64q x 48n: wave w owns q-frag w; j-frags 0..2 cover n=0..47
    f32x4 acc[3];
#pragma unroll
    for (int j = 0; j < 3; ++j) acc[j] = (f32x4){0.f, 0.f, 0.f, 0.f};
#pragma unroll
    for (int s2 = 0; s2 < 8; ++s2) {
      short8 af = *(const short8*)&As[w * 16 + l15][s2 * 32 + quad * 8];
      short8 wf[3];
#pragma unroll
      for (int t = 0; t < 3; ++t)
        wf[t] = *(const short8*)&WoaT[(size_t)(t * 16 + l15) * 256 + s2 * 32 + quad * 8];
#pragma unroll
      for (int j = 0; j < 3; ++j)
        acc[j] = __builtin_amdgcn_mfma_f32_16x16x32_bf16(af, wf[j], acc[j], 0, 0, 0);
    }
#pragma unroll
    for (int j = 0; j < 3; ++j) {
      const int n = j * 16 + l15;
#pragma unroll
      for (int r = 0; r < 4; ++r) {
        const int m = m0 + w * 16 + quad * 4 + r;
        const int q = n0 + w * 16 + quad * 4 + r;
        RAW[(size_t)m * 48 + n] = acc[j][r] + QP[q * 48 + n];
      }
    }
  }
}

// -----------------------------------------------------------------------------
// K2: fused sampling + out-projection + residual (round-0 baseline).
// Block = 64 queries of one batch; XCD swizzle: batch = blk&7.
// [r7 lesson: S2's lane->address map (8 lanes x 16B contiguous per corner
// row) is what keeps FETCH_SIZE at ~34 MB; per-thread-row remap cost 5x
// over-fetch. Do not change the gather mapping without re-measuring FETCH.]
// -----------------------------------------------------------------------------
__global__ __launch_bounds__(256)
void sample_out_kernel(const float* __restrict__ RAW, const unsigned short* __restrict__ V,
                       const unsigned short* __restrict__ Wt,  // [256][256] WoT
                       const float* __restrict__ bias, const float* __restrict__ x2,
                       float* __restrict__ OUT) {
  __shared__ unsigned short Bs[64][264];         // AO tile (q x c), 33792 B
  __shared__ __align__(16) char smemA[32768];    // sidx/swgt, then fp32 out tile
  int (*sidx)[4] = (int(*)[4])smemA;             // [1024][4]
  float (*swgt)[4] = (float(*)[4])(smemA + 16384);
  float* ot = (float*)smemA;                     // [128][64] fp32 (epilogue)

  const int blk = blockIdx.x;
  const int b = blk & 7;
  const int tile = blk >> 3;                     // 64 q-tiles per batch
  const int m0 = b * 4096 + tile * 64;
  const int tid = threadIdx.x;

  // ---- S1: corner weights/indices for 64q x 4h x 4p ----
#pragma unroll
  for (int t = 0; t < 4; ++t) {
    const int trip = t * 256 + tid;
    const int q_l = trip >> 4, h = (trip >> 2) & 3, p = trip & 3;
    const int m = m0 + q_l;
    const float* raw = RAW + (size_t)m * 48;
    const float l0 = raw[32 + h * 4 + 0];
    const float l1 = raw[32 + h * 4 + 1];
    const float l2 = raw[32 + h * 4 + 2];
    const float l3 = raw[32 + h * 4 + 3];
    const float mx = fmaxf(fmaxf(l0, l1), fmaxf(l2, l3));
    const float e0 = expf(l0 - mx), e1 = expf(l1 - mx), e2 = expf(l2 - mx), e3 = expf(l3 - mx);
    const float lp = (p == 0) ? e0 : (p == 1) ? e1 : (p == 2) ? e2 : e3;
    const float attp = lp / (e0 + e1 + e2 + e3);

    const float ox = raw[h * 8 + p * 2 + 0];
    const float oy = raw[h * 8 + p * 2 + 1];
    const float px = (float)(m & 63) + ox;       // W=64 cancels the normalizer
    const float py = (float)((m >> 6) & 63) + oy;
    const float fx = floorf(px), fy = floorf(py);
    const float wx = px - fx, wy = py - fy;
    const int x0 = (int)fx, y0 = (int)fy;
#pragma unroll
    for (int c = 0; c < 4; ++c) {
      const int dx = c & 1, dy = c >> 1;
      const int xx = x0 + dx, yy = y0 + dy;
      const bool valid = (xx >= 0) & (xx < 64) & (yy >= 0) & (yy < 64);
      const float wc = (dx ? wx : 1.f - wx) * (dy ? wy : 1.f - wy) * attp;
      swgt[trip][c] = valid ? wc : 0.f;
      const int xc = min(max(xx, 0), 63), yc = min(max(yy, 0), 63);
      sidx[trip][c] = yc * 64 + xc;
    }
  }
  __syncthreads();

  // ---- S2: gather + accumulate -> Bs (bf16) ----
#pragma unroll
  for (int it = 0; it < 8; ++it) {
    const int lin = it * 256 + tid;
    const int q_l = lin >> 5, sub = lin & 31;
    const int h = sub >> 3, c8 = (sub & 7) * 8;
    const int trip0 = q_l * 16 + h * 4;
    const unsigned short* vb = V + (size_t)b * kNq * kC + h * 64 + c8;
    float acc[8] = {};
#pragma unroll
    for (int p = 0; p < 4; ++p) {
      const int4 idx = *(const int4*)&sidx[trip0 + p][0];
      const float4 wv = *(const float4*)&swgt[trip0 + p][0];
      const int ia[4] = {idx.x, idx.y, idx.z, idx.w};
      const float wa[4] = {wv.x, wv.y, wv.z, wv.w};
#pragma unroll
      for (int c = 0; c < 4; ++c) {
        const uint4 u = *(const uint4*)&vb[(size_t)ia[c] * kC];
        const float w = wa[c];
        acc[0] = fmaf(w, uasf(u.x << 16), acc[0]);
        acc[1] = fmaf(w, uasf(u.x & 0xffff0000u), acc[1]);
        acc[2] = fmaf(w, uasf(u.y << 16), acc[2]);
        acc[3] = fmaf(w, uasf(u.y & 0xffff0000u), acc[3]);
        acc[4] = fmaf(w, uasf(u.z << 16), acc[4]);
        acc[5] = fmaf(w, uasf(u.z & 0xffff0000u), acc[5]);
        acc[6] = fmaf(w, uasf(u.w << 16), acc[6]);
        acc[7] = fmaf(w, uasf(u.w & 0xffff0000u), acc[7]);
      }
    }
    short8 outv;
#pragma unroll
    for (int e = 0; e < 8; ++e) outv[e] = (short)f2bf(acc[e]);
    *(short8*)&Bs[q_l][h * 64 + c8] = outv;
  }
  __syncthreads();

  // ---- MFMA: wave w -> c-range w*64 ----
  const int lane = tid & 63, w = tid >> 6;
  const int l15 = lane & 15, quad = lane >> 4;
  f32x4 acc[4][4];
#pragma unroll
  for (int i = 0; i < 4; ++i)
#pragma unroll
    for (int j = 0; j < 4; ++j) acc[i][j] = (f32x4){0.f, 0.f, 0.f, 0.f};
#pragma unroll
  for (int s = 0; s < 8; ++s) {
    short8 wf[4], bf[4];
#pragma unroll
    for (int t = 0; t < 4; ++t)
      wf[t] = *(const short8*)&Wt[(size_t)(w * 64 + t * 16 + l15) * 256 + s * 32 + quad * 8];
#pragma unroll
    for (int t = 0; t < 4; ++t) bf[t] = *(const short8*)&Bs[t * 16 + l15][s * 32 + quad * 8];
#pragma unroll
    for (int i = 0; i < 4; ++i)
#pragma unroll
      for (int j = 0; j < 4; ++j)
        acc[i][j] = __builtin_amdgcn_mfma_f32_16x16x32_bf16(wf[i], bf[j], acc[i][j], 0, 0, 0);
  }

  // ---- Epilogue: LDS-staged transpose -> float4 stores (+bias +x2) ----
  const int whalf = w >> 1;
  const int clbase = (w & 1) * 64;
  for (int ch = 0; ch < 2; ++ch) {
    __syncthreads();
    if (whalf == ch) {
#pragma unroll
      for (int i = 0; i < 4; ++i)
#pragma unroll
        for (int j = 0; j < 4; ++j)
#pragma unroll
          for (int r = 0; r < 4; ++r)
            ot[(clbase + i * 16 + quad * 4 + r) * 64 + j * 16 + l15] = acc[i][j][r];
    }
    __syncthreads();
#pragma unroll
    for (int t = 0; t < 8; ++t) {
      const int lin = t * 256 + tid;
      const int cl = lin >> 4, q4 = (lin & 15) * 4;
      const int c = ch * 128 + cl;
      const size_t rowbase = ((size_t)b * 256 + c) * 4096 + tile * 64;
      const float4 xv = *(const float4*)&x2[rowbase + q4];
      const float bc = bias[c];
      float4 o;
      o.x = ot[cl * 64 + q4 + 0] + bc + xv.x;
      o.y = ot[cl * 64 + q4 + 1] + bc + xv.y;
      o.z = ot[cl * 64 + q4 + 2] + bc + xv.z;
      o.w = ot[cl * 64 + q4 + 3] + bc + xv.w;
      *(float4*)&OUT[rowbase + q4] = o;
    }
  }
}

// -----------------------------------------------------------------------------
extern "C" void kernel_launch(void* const* d_in, const int* in_sizes, int n_in,
                              void* d_out, int out_size, void* d_ws, size_t ws_size,
                              hipStream_t stream) {
  const float* x1 = (const float*)d_in[0];
  const float* x2 = (const float*)d_in[1];
  const float* ln1_g = (const float*)d_in[2];
  const float* ln1_b = (const float*)d_in[3];
  const float* ln2_g = (const float*)d_in[4];
  const float* ln2_b = (const float*)d_in[5];
  const float* pos_scale = (const float*)d_in[6];
  const float* W_off = (const float*)d_in[7];
  const float* b_off = (const float*)d_in[8];
  const float* W_att = (const float*)d_in[9];
  const float* b_att = (const float*)d_in[10];
  const float* W_val = (const float*)d_in[11];
  const float* b_val = (const float*)d_in[12];
  const float* W_out = (const float*)d_in[13];
  const float* b_out = (const float*)d_in[14];
  float* out = (float*)d_out;

  char* ws = (char*)d_ws;
  const size_t plane2 = (size_t)kM * kC * sizeof(unsigned short);  // 16 MiB
  unsigned short* Vb   = (unsigned short*)(ws);
  float* RAW           = (float*)(ws + plane2);
  unsigned short* WvT  = (unsigned short*)(ws + plane2 + (size_t)kM * 48 * 4);
  unsigned short* WoT  = WvT + 65536;
  unsigned short* WoaT = WoT + 65536;
  float* QP            = (float*)(WoaT + 16384);   // [4096][48] fp32

  prep_weights_kernel<<<256, 256, 0, stream>>>(W_val, W_out, W_off, W_att,
                                               b_off, b_att, pos_scale,
                                               WvT, WoT, WoaT, QP);
  fused_ln_gemm_kernel<<<1024, 256, 0, stream>>>(x1, x2, ln1_g, ln1_b, ln2_g, ln2_b,
                                                 WvT, b_val, Vb, WoaT, QP, RAW);
  sample_out_kernel<<<512, 256, 0, stream>>>(RAW, Vb, WoT, b_out, x2, out);
}

// Round 9
// 173.104 us; speedup vs baseline: 1.5285x; 1.0064x over previous
//
#include <hip/hip_runtime.h>
#include <math.h>

// (B,C,H,W)=(8,256,64,64); NH=NP=4, d=64, Nq=4096, M=B*Nq=32768.
namespace {
constexpr int kC = 256;
constexpr int kNq = 4096;
constexpr int kM = 32768;
}

typedef __attribute__((ext_vector_type(8))) short short8;
typedef __attribute__((ext_vector_type(4))) short short4v;
typedef __attribute__((ext_vector_type(4))) float f32x4;

__device__ inline unsigned short f2bf(float f) {
  union { float f; unsigned u; } v; v.f = f;
  unsigned r = (v.u + 0x7FFFu + ((v.u >> 16) & 1u)) >> 16;  // RNE
  return (unsigned short)r;
}
__device__ inline float uasf(unsigned u) {
  union { unsigned u; float f; } v; v.u = u; return v.f;
}

// -----------------------------------------------------------------------------
// K0: weight prep (bf16 + transpose) + QP table. (baseline, unchanged)
// -----------------------------------------------------------------------------
__global__ __launch_bounds__(256)
void prep_weights_kernel(const float* __restrict__ Wv, const float* __restrict__ Wo,
                         const float* __restrict__ Woff, const float* __restrict__ Watt,
                         const float* __restrict__ boff, const float* __restrict__ batt,
                         const float* __restrict__ ps,
                         unsigned short* __restrict__ WvT, unsigned short* __restrict__ WoT,
                         unsigned short* __restrict__ WoaT, float* __restrict__ QP) {
  __shared__ unsigned short Aq[16][264];
  const int blk = blockIdx.x;
  const int tid = threadIdx.x;
  const int i = blk * 256 + tid;  // 256 blocks -> i < 65536
  {
    const int n = i >> 8, k = i & 255;
    WvT[i] = f2bf(Wv[k * 256 + n]);
    WoT[i] = f2bf(Wo[k * 256 + n]);
  }
  if (i < 16384) {
    const int j = i >> 8, k = i & 255;
    float v = 0.f;
    if (j < 32) v = Woff[k * 32 + j];
    else if (j < 48) v = Watt[k * 16 + (j - 32)];
    WoaT[i] = f2bf(v);
  }

  // --- QP tile: 16 queries q = blk*16 .. +15, thread = channel ---
  const float scale = ps[0];
  const int i2 = (tid < 128) ? tid : (tid - 128);
  const float invf = powf(10000.f, -(float)(2 * i2) * (1.f / 256.f));
  const int q0 = blk * 16;
  const float a0 = (float)q0 * invf;
  float sv = sinf(a0), cv = cosf(a0);
  const float sd = sinf(invf), cd = cosf(invf);
#pragma unroll
  for (int q = 0; q < 16; ++q) {
    Aq[q][tid] = f2bf(((tid < 128) ? sv : cv) * scale);
    const float ns = sv * cd + cv * sd;
    const float nc = cv * cd - sv * sd;
    sv = ns; cv = nc;
  }
  __syncthreads();

  const int lane = tid & 63, w = tid >> 6;
  const int l15 = lane & 15, quad = lane >> 4;
  if (w < 3) {  // n-frag w covers n = w*16 .. +15 (48 live columns)
    f32x4 acc = (f32x4){0.f, 0.f, 0.f, 0.f};
#pragma unroll
    for (int s = 0; s < 8; ++s) {
      const short8 af = *(const short8*)&Aq[l15][s * 32 + quad * 8];
      short8 wf;
#pragma unroll
      for (int j = 0; j < 8; ++j) {
        const int k = s * 32 + quad * 8 + j;
        wf[j] = (short)f2bf((w < 2) ? Woff[k * 32 + w * 16 + l15]
                                    : Watt[k * 16 + l15]);
      }
      acc = __builtin_amdgcn_mfma_f32_16x16x32_bf16(af, wf, acc, 0, 0, 0);
    }
    const int n = w * 16 + l15;
    const float bn = (n < 32) ? boff[n] : batt[n - 32];
#pragma unroll
    for (int r = 0; r < 4; ++r) {
      const int q = q0 + quad * 4 + r;
      QP[q * 48 + n] = acc[r] + bn;
    }
  }
}

// -----------------------------------------------------------------------------
// K1 v11: SEGMENT-SIZE fix. r2-r8 evidence: K1 pinned at ~41 us, 1.4 TB/s
// effective, invariant to occupancy/VGPR/tile/barriers/XCD -> the limiter is
// the lane->address map itself: old mapping read 8 channel rows x 128 B per
// wave-instruction (column slices of row-major [C][Nq] at 16 KB stride);
// 128 B-granular scatter runs at ~25% of streaming BW.
// v11: q4=(tid&15)*4, cb16=(tid>>4)*16 -> each instruction reads 4 rows x
// 256 B (the full 64-q tile row). FP reduction tree preserved BIT-EXACTLY:
// per-thread stats = two sequential 8-channel chains + one add (identical
// to old thread-chain + xor8), then xor16/xor32 pair the same channel
// groups, psum per-wave over the same 64 channels. Outputs bit-identical.
// GEMM phase + epilogues unchanged from baseline.
// -----------------------------------------------------------------------------
__global__ __launch_bounds__(256, 4)
void fused_ln_gemm_kernel(const float* __restrict__ x1, const float* __restrict__ x2,
                          const float* __restrict__ ln1_g, const float* __restrict__ ln1_b,
                          const float* __restrict__ ln2_g, const float* __restrict__ ln2_b,
                          const unsigned short* __restrict__ WvT,
                          const float* __restrict__ b_val, unsigned short* __restrict__ V,
                          const unsigned short* __restrict__ WoaT,
                          const float* __restrict__ QP, float* __restrict__ RAW) {
  __shared__ unsigned short As[64][264];   // 33792 B (normalized bf16, q x c)
  __shared__ float psum[64][4];            // [q][wave]
  __shared__ float psq[64][4];
  __shared__ float smean[64];
  __shared__ float srstd[64];

  const int mode = blockIdx.x & 1;         // 0: val path (x2), 1: offatt (x1)
  const int m0 = (blockIdx.x >> 1) * 64;
  const int b = m0 >> 12;
  const int n0 = m0 & 4095;
  const int tid = threadIdx.x;
  const int lane = tid & 63, w = tid >> 6;
  const int q4 = (tid & 15) * 4;           // this thread's 4 queries
  const int cb16 = (tid >> 4) * 16;        // this thread's 16 consecutive channels
  const float* Xb = (mode ? x1 : x2) + (size_t)b * kC * kNq;
  const float* gptr = mode ? ln1_g : ln2_g;
  const float* bptr = mode ? ln1_b : ln2_b;

  float4 gm[4], bv[4];
#pragma unroll
  for (int t = 0; t < 4; ++t) {
    gm[t] = *(const float4*)&gptr[cb16 + t * 4];
    bv[t] = *(const float4*)&bptr[cb16 + t * 4];
  }

  // ---- 16 global float4 loads: per instruction, 16 lanes x 16 B cover one
  // full 256 B tile-row; 4 rows per wave-instruction (was 8 rows x 128 B) ----
  float4 v[16];
#pragma unroll
  for (int k = 0; k < 16; ++k)
    v[k] = *(const float4*)&Xb[(size_t)(cb16 + k) * kNq + n0 + q4];

  // ---- stats in registers; tree matches baseline exactly:
  // two sequential 8-chains (= old per-thread chains) + add (= old xor8) ----
  float sA[4] = {}, sqA[4] = {}, sB[4] = {}, sqB[4] = {};
#pragma unroll
  for (int k = 0; k < 8; ++k) {
    const float* e = (const float*)&v[k];
    const float* f = (const float*)&v[8 + k];
#pragma unroll
    for (int j = 0; j < 4; ++j) {
      sA[j] += e[j];  sqA[j] += e[j] * e[j];
      sB[j] += f[j];  sqB[j] += f[j] * f[j];
    }
  }
  float s[4], sq[4];
#pragma unroll
  for (int j = 0; j < 4; ++j) { s[j] = sA[j] + sB[j]; sq[j] = sqA[j] + sqB[j]; }
  // butterfly over lane bits 4..5 (same 16/32-channel pairings as baseline)
#pragma unroll
  for (int d = 16; d <= 32; d <<= 1)
#pragma unroll
    for (int j = 0; j < 4; ++j) {
      s[j] += __shfl_xor(s[j], d);
      sq[j] += __shfl_xor(sq[j], d);
    }
  if (lane < 16) {
#pragma unroll
    for (int j = 0; j < 4; ++j) {
      psum[q4 + j][w] = s[j];
      psq[q4 + j][w] = sq[j];
    }
  }
  __syncthreads();
  if (tid < 64) {
    float S = 0.f, Q = 0.f;
#pragma unroll
    for (int ww = 0; ww < 4; ++ww) { S += psum[tid][ww]; Q += psq[tid][ww]; }
    const float m = S * (1.f / 256.f);
    const float var = Q * (1.f / 256.f) - m * m;
    smean[tid] = m;
    srstd[tid] = rsqrtf(var + 1e-5f);
  }
  __syncthreads();

  // ---- normalize from registers, two b128 writes per query row ----
  {
    const float4 mn = *(const float4*)&smean[q4];
    const float4 rs = *(const float4*)&srstd[q4];
    const float* mnp = (const float*)&mn;
    const float* rsp = (const float*)&rs;
    const float* G = (const float*)gm;
    const float* Bp = (const float*)bv;
#pragma unroll
    for (int j = 0; j < 4; ++j) {
      const int row = q4 + j;
      short8 p0, p1;
#pragma unroll
      for (int k = 0; k < 8; ++k) {
        const float e0 = ((const float*)&v[k])[j];
        const float e1 = ((const float*)&v[8 + k])[j];
        p0[k] = (short)f2bf((e0 - mnp[j]) * rsp[j] * G[k] + Bp[k]);
        p1[k] = (short)f2bf((e1 - mnp[j]) * rsp[j] * G[8 + k] + Bp[8 + k]);
      }
      *(short8*)&As[row][cb16] = p0;
      *(short8*)&As[row][cb16 + 8] = p1;
    }
  }
  __syncthreads();

  const int l15 = lane & 15, quad = lane >> 4;

  if (mode == 0) {
    // 64x256 GEMM: wave w -> n-range w*64; W frags streamed from L2 (baseline)
    f32x4 acc[4][4];
#pragma unroll
    for (int i = 0; i < 4; ++i)
#pragma unroll
      for (int j = 0; j < 4; ++j) acc[i][j] = (f32x4){0.f, 0.f, 0.f, 0.f};
#pragma unroll
    for (int s2 = 0; s2 < 8; ++s2) {
      short8 af[4], wf[4];
#pragma unroll
      for (int t = 0; t < 4; ++t) af[t] = *(const short8*)&As[t * 16 + l15][s2 * 32 + quad * 8];
#pragma unroll
      for (int t = 0; t < 4; ++t)
        wf[t] = *(const short8*)&WvT[(size_t)(w * 64 + t * 16 + l15) * 256 + s2 * 32 + quad * 8];
#pragma unroll
      for (int i = 0; i < 4; ++i)
#pragma unroll
        for (int j = 0; j < 4; ++j)
          acc[i][j] = __builtin_amdgcn_mfma_f32_16x16x32_bf16(af[i], wf[j], acc[i][j], 0, 0, 0);
    }
#pragma unroll
    for (int i = 0; i < 4; ++i)
#pragma unroll
      for (int j = 0; j < 4; ++j) {
        const int n = w * 64 + j * 16 + l15;
        const float bn = b_val[n];
#pragma unroll
        for (int r = 0; r < 4; ++r) {
          const int m = m0 + i * 16 + quad * 4 + r;
          V[(size_t)m * 256 + n] = f2bf(acc[i][j][r] + bn);
        }
      }
  } else {
    // 64q x 48n: wave w owns q-frag w; j-frags 0..2 cover n=0..47 (baseline)
    f32x4 acc[3];
#pragma unroll
    for (int j = 0; j < 3; ++j) acc[j] = (f32x4){0.f, 0.f, 0.f, 0.f};
#pragma unroll
    for (int s2 = 0; s2 < 8; ++s2) {
      short8 af = *(const short8*)&As[w * 16 + l15][s2 * 32 + quad * 8];
      short8 wf[3];
#pragma unroll
      for (int t = 0; t < 3; ++t)
        wf[t] = *(const short8*)&WoaT[(size_t)(t * 16 + l15) * 256 + s2 * 32 + quad * 8];
#pragma unroll
      for (int j = 0; j < 3; ++j)
        acc[j] = __builtin_amdgcn_mfma_f32_16x16x32_bf16(af, wf[j], acc[j], 0, 0, 0);
    }
#pragma unroll
    for (int j = 0; j < 3; ++j) {
      const int n = j * 16 + l15;
#pragma unroll
      for (int r = 0; r < 4; ++r) {
        const int m = m0 + w * 16 + quad * 4 + r;
        const int q = n0 + w * 16 + quad * 4 + r;
        RAW[(size_t)m * 48 + n] = acc[j][r] + QP[q * 48 + n];
      }
    }
  }
}

// -----------------------------------------------------------------------------
// K2: fused sampling + out-projection + residual (baseline, unchanged).
// [r7 lesson: S2's lane->address map (8 lanes x 16B contiguous per corner
// row) keeps FETCH_SIZE at ~34 MB; per-thread-row remap cost 5x over-fetch.]
// -----------------------------------------------------------------------------
__global__ __launch_bounds__(256)
void sample_out_kernel(const float* __restrict__ RAW, const unsigned short* __restrict__ V,
                       const unsigned short* __restrict__ Wt,  // [256][256] WoT
                       const float* __restrict__ bias, const float* __restrict__ x2,
                       float* __restrict__ OUT) {
  __shared__ unsigned short Bs[64][264];         // AO tile (q x c), 33792 B
  __shared__ __align__(16) char smemA[32768];    // sidx/swgt, then fp32 out tile
  int (*sidx)[4] = (int(*)[4])smemA;             // [1024][4]
  float (*swgt)[4] = (float(*)[4])(smemA + 16384);
  float* ot = (float*)smemA;                     // [128][64] fp32 (epilogue)

  const int blk = blockIdx.x;
  const int b = blk & 7;
  const int tile = blk >> 3;                     // 64 q-tiles per batch
  const int m0 = b * 4096 + tile * 64;
  const int tid = threadIdx.x;

  // ---- S1: corner weights/indices for 64q x 4h x 4p ----
#pragma unroll
  for (int t = 0; t < 4; ++t) {
    const int trip = t * 256 + tid;
    const int q_l = trip >> 4, h = (trip >> 2) & 3, p = trip & 3;
    const int m = m0 + q_l;
    const float* raw = RAW + (size_t)m * 48;
    const float l0 = raw[32 + h * 4 + 0];
    const float l1 = raw[32 + h * 4 + 1];
    const float l2 = raw[32 + h * 4 + 2];
    const float l3 = raw[32 + h * 4 + 3];
    const float mx = fmaxf(fmaxf(l0, l1), fmaxf(l2, l3));
    const float e0 = expf(l0 - mx), e1 = expf(l1 - mx), e2 = expf(l2 - mx), e3 = expf(l3 - mx);
    const float lp = (p == 0) ? e0 : (p == 1) ? e1 : (p == 2) ? e2 : e3;
    const float attp = lp / (e0 + e1 + e2 + e3);

    const float ox = raw[h * 8 + p * 2 + 0];
    const float oy = raw[h * 8 + p * 2 + 1];
    const float px = (float)(m & 63) + ox;       // W=64 cancels the normalizer
    const float py = (float)((m >> 6) & 63) + oy;
    const float fx = floorf(px), fy = floorf(py);
    const float wx = px - fx, wy = py - fy;
    const int x0 = (int)fx, y0 = (int)fy;
#pragma unroll
    for (int c = 0; c < 4; ++c) {
      const int dx = c & 1, dy = c >> 1;
      const int xx = x0 + dx, yy = y0 + dy;
      const bool valid = (xx >= 0) & (xx < 64) & (yy >= 0) & (yy < 64);
      const float wc = (dx ? wx : 1.f - wx) * (dy ? wy : 1.f - wy) * attp;
      swgt[trip][c] = valid ? wc : 0.f;
      const int xc = min(max(xx, 0), 63), yc = min(max(yy, 0), 63);
      sidx[trip][c] = yc * 64 + xc;
    }
  }
  __syncthreads();

  // ---- S2: gather + accumulate -> Bs (bf16) ----
#pragma unroll
  for (int it = 0; it < 8; ++it) {
    const int lin = it * 256 + tid;
    const int q_l = lin >> 5, sub = lin & 31;
    const int h = sub >> 3, c8 = (sub & 7) * 8;
    const int trip0 = q_l * 16 + h * 4;
    const unsigned short* vb = V + (size_t)b * kNq * kC + h * 64 + c8;
    float acc[8] = {};
#pragma unroll
    for (int p = 0; p < 4; ++p) {
      const int4 idx = *(const int4*)&sidx[trip0 + p][0];
      const float4 wv = *(const float4*)&swgt[trip0 + p][0];
      const int ia[4] = {idx.x, idx.y, idx.z, idx.w};
      const float wa[4] = {wv.x, wv.y, wv.z, wv.w};
#pragma unroll
      for (int c = 0; c < 4; ++c) {
        const uint4 u = *(const uint4*)&vb[(size_t)ia[c] * kC];
        const float w = wa[c];
        acc[0] = fmaf(w, uasf(u.x << 16), acc[0]);
        acc[1] = fmaf(w, uasf(u.x & 0xffff0000u), acc[1]);
        acc[2] = fmaf(w, uasf(u.y << 16), acc[2]);
        acc[3] = fmaf(w, uasf(u.y & 0xffff0000u), acc[3]);
        acc[4] = fmaf(w, uasf(u.z << 16), acc[4]);
        acc[5] = fmaf(w, uasf(u.z & 0xffff0000u), acc[5]);
        acc[6] = fmaf(w, uasf(u.w << 16), acc[6]);
        acc[7] = fmaf(w, uasf(u.w & 0xffff0000u), acc[7]);
      }
    }
    short8 outv;
#pragma unroll
    for (int e = 0; e < 8; ++e) outv[e] = (short)f2bf(acc[e]);
    *(short8*)&Bs[q_l][h * 64 + c8] = outv;
  }
  __syncthreads();

  // ---- MFMA: wave w -> c-range w*64 ----
  const int lane = tid & 63, w = tid >> 6;
  const int l15 = lane & 15, quad = lane >> 4;
  f32x4 acc[4][4];
#pragma unroll
  for (int i = 0; i < 4; ++i)
#pragma unroll
    for (int j = 0; j < 4; ++j) acc[i][j] = (f32x4){0.f, 0.f, 0.f, 0.f};
#pragma unroll
  for (int s = 0; s < 8; ++s) {
    short8 wf[4], bf[4];
#pragma unroll
    for (int t = 0; t < 4; ++t)
      wf[t] = *(const short8*)&Wt[(size_t)(w * 64 + t * 16 + l15) * 256 + s * 32 + quad * 8];
#pragma unroll
    for (int t = 0; t < 4; ++t) bf[t] = *(const short8*)&Bs[t * 16 + l15][s * 32 + quad * 8];
#pragma unroll
    for (int i = 0; i < 4; ++i)
#pragma unroll
      for (int j = 0; j < 4; ++j)
        acc[i][j] = __builtin_amdgcn_mfma_f32_16x16x32_bf16(wf[i], bf[j], acc[i][j], 0, 0, 0);
  }

  // ---- Epilogue: LDS-staged transpose -> float4 stores (+bias +x2) ----
  const int whalf = w >> 1;
  const int clbase = (w & 1) * 64;
  for (int ch = 0; ch < 2; ++ch) {
    __syncthreads();
    if (whalf == ch) {
#pragma unroll
      for (int i = 0; i < 4; ++i)
#pragma unroll
        for (int j = 0; j < 4; ++j)
#pragma unroll
          for (int r = 0; r < 4; ++r)
            ot[(clbase + i * 16 + quad * 4 + r) * 64 + j * 16 + l15] = acc[i][j][r];
    }
    __syncthreads();
#pragma unroll
    for (int t = 0; t < 8; ++t) {
      const int lin = t * 256 + tid;
      const int cl = lin >> 4, q4 = (lin & 15) * 4;
      const int c = ch * 128 + cl;
      const size_t rowbase = ((size_t)b * 256 + c) * 4096 + tile * 64;
      const float4 xv = *(const float4*)&x2[rowbase + q4];
      const float bc = bias[c];
      float4 o;
      o.x = ot[cl * 64 + q4 + 0] + bc + xv.x;
      o.y = ot[cl * 64 + q4 + 1] + bc + xv.y;
      o.z = ot[cl * 64 + q4 + 2] + bc + xv.z;
      o.w = ot[cl * 64 + q4 + 3] + bc + xv.w;
      *(float4*)&OUT[rowbase + q4] = o;
    }
  }
}

// -----------------------------------------------------------------------------
extern "C" void kernel_launch(void* const* d_in, const int* in_sizes, int n_in,
                              void* d_out, int out_size, void* d_ws, size_t ws_size,
                              hipStream_t stream) {
  const float* x1 = (const float*)d_in[0];
  const float* x2 = (const float*)d_in[1];
  const float* ln1_g = (const float*)d_in[2];
  const float* ln1_b = (const float*)d_in[3];
  const float* ln2_g = (const float*)d_in[4];
  const float* ln2_b = (const float*)d_in[5];
  const float* pos_scale = (const float*)d_in[6];
  const float* W_off = (const float*)d_in[7];
  const float* b_off = (const float*)d_in[8];
  const float* W_att = (const float*)d_in[9];
  const float* b_att = (const float*)d_in[10];
  const float* W_val = (const float*)d_in[11];
  const float* b_val = (const float*)d_in[12];
  const float* W_out = (const float*)d_in[13];
  const float* b_out = (const float*)d_in[14];
  float* out = (float*)d_out;

  char* ws = (char*)d_ws;
  const size_t plane2 = (size_t)kM * kC * sizeof(unsigned short);  // 16 MiB
  unsigned short* Vb   = (unsigned short*)(ws);
  float* RAW           = (float*)(ws + plane2);
  unsigned short* WvT  = (unsigned short*)(ws + plane2 + (size_t)kM * 48 * 4);
  unsigned short* WoT  = WvT + 65536;
  unsigned short* WoaT = WoT + 65536;
  float* QP            = (float*)(WoaT + 16384);   // [4096][48] fp32

  prep_weights_kernel<<<256, 256, 0, stream>>>(W_val, W_out, W_off, W_att,
                                               b_off, b_att, pos_scale,
                                               WvT, WoT, WoaT, QP);
  fused_ln_gemm_kernel<<<1024, 256, 0, stream>>>(x1, x2, ln1_g, ln1_b, ln2_g, ln2_b,
                                                 WvT, b_val, Vb, WoaT, QP, RAW);
  sample_out_kernel<<<512, 256, 0, stream>>>(RAW, Vb, WoT, b_out, x2, out);
}